// Round 21
// baseline (246.639 us; speedup 1.0000x reference)
//
#include <hip/hip_runtime.h>
#include <stdint.h>

using u16 = unsigned short;
typedef __bf16 bf16x8 __attribute__((ext_vector_type(8)));
typedef float f32x4 __attribute__((ext_vector_type(4)));

__device__ __forceinline__ u16 f2bf(float f) {
  union { float f; uint32_t u; } v; v.f = f;
  uint32_t r = v.u + 0x7fffu + ((v.u >> 16) & 1u);
  return (u16)(r >> 16);
}
__device__ __forceinline__ float bf2f(u16 h) {
  union { uint32_t u; float f; } v; v.u = ((uint32_t)h) << 16;
  return v.f;
}
__device__ __forceinline__ bf16x8 ldb8(const u16* p) {
  return *reinterpret_cast<const bf16x8*>(p);
}
__device__ __forceinline__ void gload_lds16(const void* g, void* l) {
  __builtin_amdgcn_global_load_lds(
      (const __attribute__((address_space(1))) void*)g,
      (__attribute__((address_space(3))) void*)l, 16, 0, 0);
}

// ---------------- fused prep: f32->bf16 convert + 4 weight transposes -----
__global__ __launch_bounds__(256) void prep_kernel(
    const float* __restrict__ w_qkv, const float* __restrict__ w_o,
    const float* __restrict__ w_gu, const float* __restrict__ w_down,
    const float* __restrict__ hidden, u16* __restrict__ wqkv_t,
    u16* __restrict__ wo_t, u16* __restrict__ wgu_t, u16* __restrict__ wd_t,
    u16* __restrict__ xb) {
  const int b = blockIdx.x;
  const int t = threadIdx.x;

  if (b >= 12544) {  // convert job
    int idx = (b - 12544) * 256 + t;
    float4 v = *(const float4*)(hidden + (size_t)idx * 4);
    ushort4 o;
    o.x = f2bf(v.x); o.y = f2bf(v.y); o.z = f2bf(v.z); o.w = f2bf(v.w);
    *(ushort4*)(xb + (size_t)idx * 4) = o;
    return;
  }

  const float* W;
  u16* Wt;
  int N, K, lb;
  bool perm = false;
  if (b < 3072)      { W = w_qkv; Wt = wqkv_t; N = 3072; K = 1024; lb = b; }
  else if (b < 4096) { W = w_o;   Wt = wo_t;   N = 1024; K = 1024; lb = b - 3072; }
  else if (b < 9728) { W = w_gu;  Wt = wgu_t;  N = 5632; K = 1024; lb = b - 4096; perm = true; }
  else               { W = w_down; Wt = wd_t;  N = 1024; K = 2816; lb = b - 9728; }

  const int nx = N >> 5;
  const int n0 = (lb % nx) * 32, k0 = (lb / nx) * 32;
  const int tx = t & 31, ty = t >> 5;  // (32, 8)

  __shared__ u16 tile[32][33];
  const int nc = n0 + tx;
  const int src_col = perm ? (((nc & 1) == 0) ? (nc >> 1) : 2816 + (nc >> 1))
                           : nc;
#pragma unroll
  for (int i = 0; i < 32; i += 8)
    tile[ty + i][tx] = f2bf(W[(size_t)(k0 + ty + i) * N + src_col]);
  __syncthreads();
#pragma unroll
  for (int i = 0; i < 32; i += 8)
    Wt[(size_t)(n0 + ty + i) * K + k0 + tx] = tile[tx][ty + i];
}

// ---------------- GEMM 128x128 + fused RoPE/V-transpose, 2-phase ----------
__global__ __launch_bounds__(256) void gemm_qkv_rope(
    const u16* __restrict__ A, const u16* __restrict__ Bt,
    const float* __restrict__ cosb, const float* __restrict__ sinb,
    u16* __restrict__ qb, u16* __restrict__ kb, u16* __restrict__ vt,
    int M, int N, int K) {
  __shared__ __align__(16) u16 As[2][128 * 32];
  __shared__ __align__(16) u16 Bs[2][128 * 32];
  __shared__ u16 vbuf[4][64][17];
  const int tid = threadIdx.x;
  const int w = tid >> 6, lane = tid & 63;
  const int wr = w >> 1, wc = w & 1;
  const int r16 = lane & 15, g = lane >> 4;
  const int nwg = gridDim.x * gridDim.y;
  const int idx = blockIdx.y * gridDim.x + blockIdx.x;
  const int swz = (idx & 7) * (nwg >> 3) + (idx >> 3);  // bijective, nwg%8==0
  const int m0 = (swz / gridDim.x) * 128, n0 = (swz % gridDim.x) * 128;
  const int ldrow = lane >> 2;
  const int ldk = (lane & 3) * 8;
  const int NT = K >> 5;

  f32x4 acc[4][4] = {};

#define STG_QKV(tt, b_)                                                   \
  do {                                                                    \
    const int kt_ = (tt) * 32;                                            \
    _Pragma("unroll") for (int i = 0; i < 2; ++i) {                       \
      int chunk = w * 2 + i;                                              \
      int row = chunk * 16 + ldrow;                                       \
      gload_lds16(A + (size_t)(m0 + row) * K + kt_ + ldk,                 \
                  &As[b_][chunk * 512]);                                  \
      gload_lds16(Bt + (size_t)(n0 + row) * K + kt_ + ldk,                \
                  &Bs[b_][chunk * 512]);                                  \
    }                                                                     \
  } while (0)

  STG_QKV(0, 0);
  asm volatile("s_waitcnt vmcnt(0)" ::: "memory");
  __builtin_amdgcn_s_barrier();

  int cur = 0;
  for (int t = 0; t < NT; ++t) {
    if (t + 1 < NT) STG_QKV(t + 1, cur ^ 1);
    bf16x8 a[4], b[4];
#pragma unroll
    for (int mt = 0; mt < 4; ++mt)
      a[mt] = ldb8(&As[cur][(wr * 64 + mt * 16 + r16) * 32 + g * 8]);
#pragma unroll
    for (int nt = 0; nt < 4; ++nt)
      b[nt] = ldb8(&Bs[cur][(wc * 64 + nt * 16 + r16) * 32 + g * 8]);
#pragma unroll
    for (int mt = 0; mt < 4; ++mt)
#pragma unroll
      for (int nt = 0; nt < 4; ++nt)
        acc[mt][nt] = __builtin_amdgcn_mfma_f32_16x16x32_bf16(
            a[mt], b[nt], acc[mt][nt], 0, 0, 0);
    asm volatile("s_waitcnt vmcnt(0) lgkmcnt(0)" ::: "memory");
    __builtin_amdgcn_s_barrier();
    cur ^= 1;
  }

  const int type = n0 >> 10;                  // 0=q, 1=k, 2=v
  const int head = ((n0 & 1023) >> 6) + wc;   // 2 heads per tile, wc picks
  if (type < 2) {
    u16* outp = type == 0 ? qb : kb;
    const float qs = type == 0 ? 0.125f : 1.0f;
#pragma unroll
    for (int mt = 0; mt < 4; ++mt)
#pragma unroll
      for (int r = 0; r < 4; ++r) {
        const int srow = m0 + wr * 64 + mt * 16 + g * 4 + r;
#pragma unroll
        for (int nt = 0; nt < 4; ++nt) {
          const int d = nt * 16 + r16;
          float cv = cosb[srow * 64 + d];
          float sv = sinb[srow * 64 + d];
          float sgn = nt < 2 ? -1.f : 1.f;
          float val = acc[mt][nt][r] * cv + sgn * acc[mt][nt ^ 2][r] * sv;
          outp[((size_t)head * 2048 + srow) * 64 + d] = f2bf(val * qs);
        }
      }
  } else {
    const int s_base = m0 + wr * 64;
    const int dl = lane >> 2;          // 0..15: d within 16-chunk
    const int sblk = (lane & 3) * 16;  // 0,16,32,48: s sub-block
#pragma unroll
    for (int nt = 0; nt < 4; ++nt) {
#pragma unroll
      for (int mt = 0; mt < 4; ++mt)
#pragma unroll
        for (int r = 0; r < 4; ++r)
          vbuf[w][mt * 16 + g * 4 + r][r16] = f2bf(acc[mt][nt][r]);
      u16* dst =
          vt + ((size_t)(head * 64 + nt * 16 + dl)) * 2048 + s_base + sblk;
#pragma unroll
      for (int jj = 0; jj < 4; ++jj) {
        ushort4 ov;
        ov.x = vbuf[w][sblk + jj * 4 + 0][dl];
        ov.y = vbuf[w][sblk + jj * 4 + 1][dl];
        ov.z = vbuf[w][sblk + jj * 4 + 2][dl];
        ov.w = vbuf[w][sblk + jj * 4 + 3][dl];
        *(ushort4*)(dst + jj * 4) = ov;
      }
    }
  }
}

// ---------------- GEMM 128x128 + fused SwiGLU, 2-phase --------------------
__global__ __launch_bounds__(256) void gemm_bt_swiglu(
    const u16* __restrict__ A, const u16* __restrict__ Bt,
    u16* __restrict__ Hb, int M, int N, int K) {
  __shared__ __align__(16) u16 As[2][128 * 32];
  __shared__ __align__(16) u16 Bs[2][128 * 32];
  const int tid = threadIdx.x;
  const int w = tid >> 6, lane = tid & 63;
  const int wr = w >> 1, wc = w & 1;
  const int r16 = lane & 15, g = lane >> 4;
  const int nwg = gridDim.x * gridDim.y;
  const int idx = blockIdx.y * gridDim.x + blockIdx.x;
  const int swz = (idx & 7) * (nwg >> 3) + (idx >> 3);
  const int m0 = (swz / gridDim.x) * 128, n0 = (swz % gridDim.x) * 128;
  const int ldrow = lane >> 2;
  const int ldk = (lane & 3) * 8;
  const int NT = K >> 5;

  f32x4 acc[4][4] = {};

  STG_QKV(0, 0);
  asm volatile("s_waitcnt vmcnt(0)" ::: "memory");
  __builtin_amdgcn_s_barrier();

  int cur = 0;
  for (int t = 0; t < NT; ++t) {
    if (t + 1 < NT) STG_QKV(t + 1, cur ^ 1);
    bf16x8 a[4], b[4];
#pragma unroll
    for (int mt = 0; mt < 4; ++mt)
      a[mt] = ldb8(&As[cur][(wr * 64 + mt * 16 + r16) * 32 + g * 8]);
#pragma unroll
    for (int nt = 0; nt < 4; ++nt)
      b[nt] = ldb8(&Bs[cur][(wc * 64 + nt * 16 + r16) * 32 + g * 8]);
#pragma unroll
    for (int mt = 0; mt < 4; ++mt)
#pragma unroll
      for (int nt = 0; nt < 4; ++nt)
        acc[mt][nt] = __builtin_amdgcn_mfma_f32_16x16x32_bf16(
            a[mt], b[nt], acc[mt][nt], 0, 0, 0);
    asm volatile("s_waitcnt vmcnt(0) lgkmcnt(0)" ::: "memory");
    __builtin_amdgcn_s_barrier();
    cur ^= 1;
  }
#pragma unroll
  for (int mt = 0; mt < 4; ++mt)
#pragma unroll
    for (int nt = 0; nt < 4; ++nt)
#pragma unroll
      for (int r = 0; r < 4; ++r) {
        float val = acc[mt][nt][r];
        float other = __shfl_xor(val, 1);  // all lanes participate
        if ((r16 & 1) == 0) {
          float o = val / (1.f + __expf(-val)) * other;  // silu(gate)*up
          int row = m0 + wr * 64 + mt * 16 + g * 4 + r;
          int col = n0 + wc * 64 + nt * 16 + r16;
          Hb[(size_t)row * 2816 + (col >> 1)] = f2bf(o);
        }
      }
}

// ---------------- GEMM 64x64, 2-phase, 512 blocks = 2/CU ------------------
__global__ __launch_bounds__(256) void gemm_bt6464(
    const u16* __restrict__ A, const u16* __restrict__ Bt,
    u16* __restrict__ C, int M, int N, int K) {
  __shared__ __align__(16) u16 As[2][64 * 32];
  __shared__ __align__(16) u16 Bs[2][64 * 32];
  const int tid = threadIdx.x;
  const int w = tid >> 6, lane = tid & 63;
  const int wr = w >> 1, wc = w & 1;
  const int r16 = lane & 15, g = lane >> 4;
  const int nwg = gridDim.x * gridDim.y;
  const int idx = blockIdx.y * gridDim.x + blockIdx.x;
  const int swz = (idx & 7) * (nwg >> 3) + (idx >> 3);  // bijective, nwg%8==0
  const int m0 = (swz / gridDim.x) * 64, n0 = (swz % gridDim.x) * 64;
  const int ldrow = lane >> 2;
  const int ldk = (lane & 3) * 8;
  const int NT = K >> 5;

  f32x4 acc[2][2] = {};

#define STG_6464(tt, b_)                                                  \
  do {                                                                    \
    const int kt_ = (tt) * 32;                                            \
    _Pragma("unroll") for (int i = 0; i < 2; ++i) {                       \
      int chunk = w * 2 + i;                                              \
      if (chunk < 4) {                                                    \
        int row = chunk * 16 + ldrow;                                     \
        gload_lds16(A + (size_t)(m0 + row) * K + kt_ + ldk,               \
                    &As[b_][chunk * 512]);                                \
      } else {                                                            \
        int cb = chunk - 4;                                               \
        int row = cb * 16 + ldrow;                                        \
        gload_lds16(Bt + (size_t)(n0 + row) * K + kt_ + ldk,              \
                    &Bs[b_][cb * 512]);                                   \
      }                                                                   \
    }                                                                     \
  } while (0)

  STG_6464(0, 0);
  asm volatile("s_waitcnt vmcnt(0)" ::: "memory");
  __builtin_amdgcn_s_barrier();

  int cur = 0;
  for (int t = 0; t < NT; ++t) {
    if (t + 1 < NT) STG_6464(t + 1, cur ^ 1);
    bf16x8 a[2], b[2];
#pragma unroll
    for (int mt = 0; mt < 2; ++mt)
      a[mt] = ldb8(&As[cur][(wr * 32 + mt * 16 + r16) * 32 + g * 8]);
#pragma unroll
    for (int nt = 0; nt < 2; ++nt)
      b[nt] = ldb8(&Bs[cur][(wc * 32 + nt * 16 + r16) * 32 + g * 8]);
#pragma unroll
    for (int mt = 0; mt < 2; ++mt)
#pragma unroll
      for (int nt = 0; nt < 2; ++nt)
        acc[mt][nt] = __builtin_amdgcn_mfma_f32_16x16x32_bf16(
            a[mt], b[nt], acc[mt][nt], 0, 0, 0);
    asm volatile("s_waitcnt vmcnt(0) lgkmcnt(0)" ::: "memory");
    __builtin_amdgcn_s_barrier();
    cur ^= 1;
  }
#pragma unroll
  for (int mt = 0; mt < 2; ++mt)
#pragma unroll
    for (int nt = 0; nt < 2; ++nt)
#pragma unroll
      for (int r = 0; r < 4; ++r) {
        int row = m0 + wr * 32 + mt * 16 + g * 4 + r;
        int col = n0 + wc * 32 + nt * 16 + r16;
        C[(size_t)row * N + col] = f2bf(acc[mt][nt][r]);
      }
}

// ---------------- flash attention: 8 waves/block = 16 waves/CU ------------
// R20 body byte-identical (swapped QK^T, batched loads); structural change
// only: 512-thread/8-wave blocks, wave w owns KV [w*256, +256); 8-way
// combine (R11's verified indexing). __launch_bounds__(512,2) keeps the
// VGPR cap at 256 (R11's failure was the (512,4) clamp to 128 -> spill).
// Same 64-q-row geometry -> same FETCH; doubles TLP (grid was the limit).
__global__ __launch_bounds__(512, 2) void attn_kernel(
    const u16* __restrict__ qb, const u16* __restrict__ kb,
    const u16* __restrict__ vt, const float* __restrict__ bias,
    u16* __restrict__ attnb) {
  const int bid = blockIdx.x;
  const int swz = (bid & 7) * 64 + (bid >> 3);
  const int h = swz >> 5;
  const int qt = swz & 31;
  const int tid = threadIdx.x;
  const int w = tid >> 6;        // 0..7
  const int lane = tid & 63;
  const int r16 = lane & 15, g = lane >> 4;

  __shared__ __align__(16) u16 P_lds[8][16 * 40];
  __shared__ float acc_s[8][16][64];
  __shared__ float m_s[8][16], l_s[8][16];

  bf16x8 qf0[4], qf1[4];
#pragma unroll
  for (int st = 0; st < 4; ++st) {
    const u16* qrow =
        qb + ((size_t)h * 2048 + qt * 64 + st * 16 + r16) * 64;
    qf0[st] = ldb8(qrow + g * 8);
    qf1[st] = ldb8(qrow + 32 + g * 8);
  }

  f32x4 acc[4][4] = {};
  float m[4], lsum[4];  // per-lane: q = r16
#pragma unroll
  for (int st = 0; st < 4; ++st) { m[st] = -1e30f; lsum[st] = 0.f; }

  const float* bbase = bias + ((size_t)h * 2048 + qt * 64) * 2048;

  const int kv0 = w * 256, kv1 = kv0 + 256;
  for (int kt = kv0; kt < kv1; kt += 32) {
    // batched loads: K, V, and ALL subtiles' bias (one latency exposure)
    bf16x8 ka[2], kc[2];
#pragma unroll
    for (int c = 0; c < 2; ++c) {
      const u16* krow = kb + ((size_t)h * 2048 + kt + c * 16 + r16) * 64;
      ka[c] = ldb8(krow + g * 8);
      kc[c] = ldb8(krow + 32 + g * 8);
    }
    bf16x8 vf[4];
#pragma unroll
    for (int nt = 0; nt < 4; ++nt)
      vf[nt] =
          ldb8(vt + ((size_t)h * 64 + nt * 16 + r16) * 2048 + kt + g * 8);
    float4 bv[4][2];
#pragma unroll
    for (int st = 0; st < 4; ++st) {
      bv[st][0] = *(const float4*)(bbase +
          (size_t)(st * 16 + r16) * 2048 + kt + g * 4);
      bv[st][1] = *(const float4*)(bbase +
          (size_t)(st * 16 + r16) * 2048 + kt + 16 + g * 4);
    }

#pragma unroll
    for (int st = 0; st < 4; ++st) {
      f32x4 sc[2];
#pragma unroll
      for (int c = 0; c < 2; ++c) {
        f32x4 z = {0.f, 0.f, 0.f, 0.f};
        f32x4 t =
            __builtin_amdgcn_mfma_f32_16x16x32_bf16(ka[c], qf0[st], z, 0, 0, 0);
        sc[c] =
            __builtin_amdgcn_mfma_f32_16x16x32_bf16(kc[c], qf1[st], t, 0, 0, 0);
      }
      sc[0][0] += bv[st][0].x; sc[0][1] += bv[st][0].y;
      sc[0][2] += bv[st][0].z; sc[0][3] += bv[st][0].w;
      sc[1][0] += bv[st][1].x; sc[1][1] += bv[st][1].y;
      sc[1][2] += bv[st][1].z; sc[1][3] += bv[st][1].w;

      float t8 = fmaxf(fmaxf(fmaxf(sc[0][0], sc[0][1]), fmaxf(sc[0][2], sc[0][3])),
                       fmaxf(fmaxf(sc[1][0], sc[1][1]), fmaxf(sc[1][2], sc[1][3])));
      t8 = fmaxf(t8, __shfl_xor(t8, 16));
      t8 = fmaxf(t8, __shfl_xor(t8, 32));
      float mnew = fmaxf(m[st], t8);
      float alpha = __expf(m[st] - mnew);
      m[st] = mnew;

      float ps = 0.f;
#pragma unroll
      for (int c = 0; c < 2; ++c)
#pragma unroll
        for (int r = 0; r < 4; ++r) {
          float p = __expf(sc[c][r] - mnew);
          sc[c][r] = p;
          ps += p;
        }
      lsum[st] = lsum[st] * alpha + ps;

      float av[4];
#pragma unroll
      for (int r = 0; r < 4; ++r) av[r] = __shfl(alpha, g * 4 + r);
#pragma unroll
      for (int nt = 0; nt < 4; ++nt)
#pragma unroll
        for (int r = 0; r < 4; ++r) acc[st][nt][r] *= av[r];

#pragma unroll
      for (int c = 0; c < 2; ++c)
#pragma unroll
        for (int r = 0; r < 4; ++r)
          P_lds[w][r16 * 40 + c * 16 + g * 4 + r] = f2bf(sc[c][r]);
      bf16x8 pf = ldb8(&P_lds[w][r16 * 40 + g * 8]);
#pragma unroll
      for (int nt = 0; nt < 4; ++nt)
        acc[st][nt] = __builtin_amdgcn_mfma_f32_16x16x32_bf16(
            pf, vf[nt], acc[st][nt], 0, 0, 0);
    }
  }

#pragma unroll
  for (int st = 0; st < 4; ++st) {
    __syncthreads();
#pragma unroll
    for (int nt = 0; nt < 4; ++nt)
#pragma unroll
      for (int r = 0; r < 4; ++r)
        acc_s[w][g * 4 + r][nt * 16 + r16] = acc[st][nt][r];
    {
      float t = lsum[st];
      t += __shfl_xor(t, 16);
      t += __shfl_xor(t, 32);
      if (lane < 16) {
        l_s[w][r16] = t;
        m_s[w][r16] = m[st];
      }
    }
    __syncthreads();

    // 8-way combine: 512 threads x 2 outputs (R11-verified indexing)
    const int row = tid >> 5;         // 0..15
    const int col2 = (tid & 31) * 2;  // 0..62 step 2
    float mm = m_s[0][row];
#pragma unroll
    for (int w8 = 1; w8 < 8; ++w8) mm = fmaxf(mm, m_s[w8][row]);
    float sw[8];
    float ltot = 0.f;
#pragma unroll
    for (int w8 = 0; w8 < 8; ++w8) {
      sw[w8] = __expf(m_s[w8][row] - mm);
      ltot += l_s[w8][row] * sw[w8];
    }
    float inv = 1.f / ltot;
    float v0 = 0.f, v1 = 0.f;
#pragma unroll
    for (int w8 = 0; w8 < 8; ++w8) {
      v0 += acc_s[w8][row][col2] * sw[w8];
      v1 += acc_s[w8][row][col2 + 1] * sw[w8];
    }
    ushort2 ov;
    ov.x = f2bf(v0 * inv);
    ov.y = f2bf(v1 * inv);
    *(ushort2*)(attnb + (size_t)(qt * 64 + st * 16 + row) * 1024 + h * 64 +
                col2) = ov;
  }
}

// ---------------- residual add + RMSNorm ----------------------------------
__global__ __launch_bounds__(256) void addnorm_kernel(
    const float* __restrict__ resid, const u16* __restrict__ delta,
    float* __restrict__ outf, u16* __restrict__ outb) {
  int row = blockIdx.x, tid = threadIdx.x;
  size_t base = (size_t)row * 1024 + tid * 4;
  float4 rv = *(const float4*)(resid + base);
  ushort4 dv = *(const ushort4*)(delta + base);
  float x0 = rv.x + bf2f(dv.x);
  float x1 = rv.y + bf2f(dv.y);
  float x2 = rv.z + bf2f(dv.z);
  float x3 = rv.w + bf2f(dv.w);
  float ss = x0 * x0 + x1 * x1 + x2 * x2 + x3 * x3;
#pragma unroll
  for (int sh = 32; sh >= 1; sh >>= 1) ss += __shfl_xor(ss, sh);
  __shared__ float red[4];
  if ((tid & 63) == 0) red[tid >> 6] = ss;
  __syncthreads();
  float tot = red[0] + red[1] + red[2] + red[3];
  float rstd = rsqrtf(tot * (1.0f / 1024.0f) + 1e-5f);
  float4 ov;
  ov.x = x0 * rstd; ov.y = x1 * rstd; ov.z = x2 * rstd; ov.w = x3 * rstd;
  *(float4*)(outf + base) = ov;
  if (outb) {
    ushort4 ob;
    ob.x = f2bf(ov.x); ob.y = f2bf(ov.y); ob.z = f2bf(ov.z); ob.w = f2bf(ov.w);
    *(ushort4*)(outb + base) = ob;
  }
}

extern "C" void kernel_launch(void* const* d_in, const int* in_sizes, int n_in,
                              void* d_out, int out_size, void* d_ws,
                              size_t ws_size, hipStream_t stream) {
  (void)in_sizes; (void)n_in; (void)out_size; (void)ws_size;
  const float* cosb  = (const float*)d_in[0];
  const float* sinb  = (const float*)d_in[1];
  const float* hidden = (const float*)d_in[2];
  const float* bias  = (const float*)d_in[3];
  const float* w_qkv = (const float*)d_in[4];
  const float* w_o   = (const float*)d_in[5];
  const float* w_gu  = (const float*)d_in[6];
  const float* w_down = (const float*)d_in[7];
  float* out = (float*)d_out;

  char* p = (char*)d_ws;
  auto alloc = [&](size_t bytes) {
    void* r = (void*)p;
    p += (bytes + 255) & ~(size_t)255;
    return r;
  };
  u16* wqkv_t = (u16*)alloc((size_t)3072 * 1024 * 2);
  u16* wo_t   = (u16*)alloc((size_t)1024 * 1024 * 2);
  u16* wgu_t  = (u16*)alloc((size_t)5632 * 1024 * 2);
  u16* wd_t   = (u16*)alloc((size_t)1024 * 2816 * 2);
  u16* xb     = (u16*)alloc((size_t)2048 * 1024 * 2);
  u16* qb     = (u16*)alloc((size_t)16 * 2048 * 64 * 2);
  u16* kb     = (u16*)alloc((size_t)16 * 2048 * 64 * 2);
  u16* vt     = (u16*)alloc((size_t)16 * 2048 * 64 * 2);
  u16* attnb  = (u16*)alloc((size_t)2048 * 1024 * 2);
  u16* ob     = (u16*)alloc((size_t)2048 * 1024 * 2);
  float* x1f  = (float*)alloc((size_t)2048 * 1024 * 4);
  u16* x1b    = (u16*)alloc((size_t)2048 * 1024 * 2);
  u16* hb     = (u16*)alloc((size_t)2048 * 2816 * 2);
  u16* mlpb   = (u16*)alloc((size_t)2048 * 1024 * 2);

  prep_kernel<<<14592, 256, 0, stream>>>(w_qkv, w_o, w_gu, w_down, hidden,
                                         wqkv_t, wo_t, wgu_t, wd_t, xb);

  gemm_qkv_rope<<<dim3(3072 / 128, 2048 / 128), 256, 0, stream>>>(
      xb, wqkv_t, cosb, sinb, qb, kb, vt, 2048, 3072, 1024);
  attn_kernel<<<512, 512, 0, stream>>>(qb, kb, vt, bias, attnb);
  gemm_bt6464<<<dim3(1024 / 64, 2048 / 64), 256, 0, stream>>>(attnb, wo_t, ob, 2048, 1024, 1024);
  addnorm_kernel<<<2048, 256, 0, stream>>>(hidden, ob, x1f, x1b);
  gemm_bt_swiglu<<<dim3(5632 / 128, 2048 / 128), 256, 0, stream>>>(x1b, wgu_t, hb, 2048, 5632, 1024);
  gemm_bt6464<<<dim3(1024 / 64, 2048 / 64), 256, 0, stream>>>(hb, wd_t, mlpb, 2048, 1024, 2816);
  addnorm_kernel<<<2048, 256, 0, stream>>>(x1f, mlpb, out, nullptr);
}

// Round 22
// 240.013 us; speedup vs baseline: 1.0276x; 1.0276x over previous
//
#include <hip/hip_runtime.h>
#include <stdint.h>

using u16 = unsigned short;
typedef __bf16 bf16x8 __attribute__((ext_vector_type(8)));
typedef float f32x4 __attribute__((ext_vector_type(4)));

__device__ __forceinline__ u16 f2bf(float f) {
  union { float f; uint32_t u; } v; v.f = f;
  uint32_t r = v.u + 0x7fffu + ((v.u >> 16) & 1u);
  return (u16)(r >> 16);
}
__device__ __forceinline__ float bf2f(u16 h) {
  union { uint32_t u; float f; } v; v.u = ((uint32_t)h) << 16;
  return v.f;
}
__device__ __forceinline__ bf16x8 ldb8(const u16* p) {
  return *reinterpret_cast<const bf16x8*>(p);
}
__device__ __forceinline__ void gload_lds16(const void* g, void* l) {
  __builtin_amdgcn_global_load_lds(
      (const __attribute__((address_space(1))) void*)g,
      (__attribute__((address_space(3))) void*)l, 16, 0, 0);
}

// ---------------- fused prep: f32->bf16 convert + 4 weight transposes -----
__global__ __launch_bounds__(256) void prep_kernel(
    const float* __restrict__ w_qkv, const float* __restrict__ w_o,
    const float* __restrict__ w_gu, const float* __restrict__ w_down,
    const float* __restrict__ hidden, u16* __restrict__ wqkv_t,
    u16* __restrict__ wo_t, u16* __restrict__ wgu_t, u16* __restrict__ wd_t,
    u16* __restrict__ xb) {
  const int b = blockIdx.x;
  const int t = threadIdx.x;

  if (b >= 12544) {  // convert job
    int idx = (b - 12544) * 256 + t;
    float4 v = *(const float4*)(hidden + (size_t)idx * 4);
    ushort4 o;
    o.x = f2bf(v.x); o.y = f2bf(v.y); o.z = f2bf(v.z); o.w = f2bf(v.w);
    *(ushort4*)(xb + (size_t)idx * 4) = o;
    return;
  }

  const float* W;
  u16* Wt;
  int N, K, lb;
  bool perm = false;
  if (b < 3072)      { W = w_qkv; Wt = wqkv_t; N = 3072; K = 1024; lb = b; }
  else if (b < 4096) { W = w_o;   Wt = wo_t;   N = 1024; K = 1024; lb = b - 3072; }
  else if (b < 9728) { W = w_gu;  Wt = wgu_t;  N = 5632; K = 1024; lb = b - 4096; perm = true; }
  else               { W = w_down; Wt = wd_t;  N = 1024; K = 2816; lb = b - 9728; }

  const int nx = N >> 5;
  const int n0 = (lb % nx) * 32, k0 = (lb / nx) * 32;
  const int tx = t & 31, ty = t >> 5;  // (32, 8)

  __shared__ u16 tile[32][33];
  const int nc = n0 + tx;
  const int src_col = perm ? (((nc & 1) == 0) ? (nc >> 1) : 2816 + (nc >> 1))
                           : nc;
#pragma unroll
  for (int i = 0; i < 32; i += 8)
    tile[ty + i][tx] = f2bf(W[(size_t)(k0 + ty + i) * N + src_col]);
  __syncthreads();
#pragma unroll
  for (int i = 0; i < 32; i += 8)
    Wt[(size_t)(n0 + ty + i) * K + k0 + tx] = tile[tx][ty + i];
}

// ---------------- GEMM 128x128 + fused RoPE/V-transpose, 2-phase ----------
__global__ __launch_bounds__(256) void gemm_qkv_rope(
    const u16* __restrict__ A, const u16* __restrict__ Bt,
    const float* __restrict__ cosb, const float* __restrict__ sinb,
    u16* __restrict__ qb, u16* __restrict__ kb, u16* __restrict__ vt,
    int M, int N, int K) {
  __shared__ __align__(16) u16 As[2][128 * 32];
  __shared__ __align__(16) u16 Bs[2][128 * 32];
  __shared__ u16 vbuf[4][64][17];
  const int tid = threadIdx.x;
  const int w = tid >> 6, lane = tid & 63;
  const int wr = w >> 1, wc = w & 1;
  const int r16 = lane & 15, g = lane >> 4;
  const int nwg = gridDim.x * gridDim.y;
  const int idx = blockIdx.y * gridDim.x + blockIdx.x;
  const int swz = (idx & 7) * (nwg >> 3) + (idx >> 3);  // bijective, nwg%8==0
  const int m0 = (swz / gridDim.x) * 128, n0 = (swz % gridDim.x) * 128;
  const int ldrow = lane >> 2;
  const int ldk = (lane & 3) * 8;
  const int NT = K >> 5;

  f32x4 acc[4][4] = {};

#define STG_QKV(tt, b_)                                                   \
  do {                                                                    \
    const int kt_ = (tt) * 32;                                            \
    _Pragma("unroll") for (int i = 0; i < 2; ++i) {                       \
      int chunk = w * 2 + i;                                              \
      int row = chunk * 16 + ldrow;                                       \
      gload_lds16(A + (size_t)(m0 + row) * K + kt_ + ldk,                 \
                  &As[b_][chunk * 512]);                                  \
      gload_lds16(Bt + (size_t)(n0 + row) * K + kt_ + ldk,                \
                  &Bs[b_][chunk * 512]);                                  \
    }                                                                     \
  } while (0)

  STG_QKV(0, 0);
  asm volatile("s_waitcnt vmcnt(0)" ::: "memory");
  __builtin_amdgcn_s_barrier();

  int cur = 0;
  for (int t = 0; t < NT; ++t) {
    if (t + 1 < NT) STG_QKV(t + 1, cur ^ 1);
    bf16x8 a[4], b[4];
#pragma unroll
    for (int mt = 0; mt < 4; ++mt)
      a[mt] = ldb8(&As[cur][(wr * 64 + mt * 16 + r16) * 32 + g * 8]);
#pragma unroll
    for (int nt = 0; nt < 4; ++nt)
      b[nt] = ldb8(&Bs[cur][(wc * 64 + nt * 16 + r16) * 32 + g * 8]);
#pragma unroll
    for (int mt = 0; mt < 4; ++mt)
#pragma unroll
      for (int nt = 0; nt < 4; ++nt)
        acc[mt][nt] = __builtin_amdgcn_mfma_f32_16x16x32_bf16(
            a[mt], b[nt], acc[mt][nt], 0, 0, 0);
    asm volatile("s_waitcnt vmcnt(0) lgkmcnt(0)" ::: "memory");
    __builtin_amdgcn_s_barrier();
    cur ^= 1;
  }

  const int type = n0 >> 10;                  // 0=q, 1=k, 2=v
  const int head = ((n0 & 1023) >> 6) + wc;   // 2 heads per tile, wc picks
  if (type < 2) {
    u16* outp = type == 0 ? qb : kb;
    const float qs = type == 0 ? 0.125f : 1.0f;
#pragma unroll
    for (int mt = 0; mt < 4; ++mt)
#pragma unroll
      for (int r = 0; r < 4; ++r) {
        const int srow = m0 + wr * 64 + mt * 16 + g * 4 + r;
#pragma unroll
        for (int nt = 0; nt < 4; ++nt) {
          const int d = nt * 16 + r16;
          float cv = cosb[srow * 64 + d];
          float sv = sinb[srow * 64 + d];
          float sgn = nt < 2 ? -1.f : 1.f;
          float val = acc[mt][nt][r] * cv + sgn * acc[mt][nt ^ 2][r] * sv;
          outp[((size_t)head * 2048 + srow) * 64 + d] = f2bf(val * qs);
        }
      }
  } else {
    const int s_base = m0 + wr * 64;
    const int dl = lane >> 2;          // 0..15: d within 16-chunk
    const int sblk = (lane & 3) * 16;  // 0,16,32,48: s sub-block
#pragma unroll
    for (int nt = 0; nt < 4; ++nt) {
#pragma unroll
      for (int mt = 0; mt < 4; ++mt)
#pragma unroll
        for (int r = 0; r < 4; ++r)
          vbuf[w][mt * 16 + g * 4 + r][r16] = f2bf(acc[mt][nt][r]);
      u16* dst =
          vt + ((size_t)(head * 64 + nt * 16 + dl)) * 2048 + s_base + sblk;
#pragma unroll
      for (int jj = 0; jj < 4; ++jj) {
        ushort4 ov;
        ov.x = vbuf[w][sblk + jj * 4 + 0][dl];
        ov.y = vbuf[w][sblk + jj * 4 + 1][dl];
        ov.z = vbuf[w][sblk + jj * 4 + 2][dl];
        ov.w = vbuf[w][sblk + jj * 4 + 3][dl];
        *(ushort4*)(dst + jj * 4) = ov;
      }
    }
  }
}

// ---------------- GEMM 128x128 + fused SwiGLU, 2-phase --------------------
__global__ __launch_bounds__(256) void gemm_bt_swiglu(
    const u16* __restrict__ A, const u16* __restrict__ Bt,
    u16* __restrict__ Hb, int M, int N, int K) {
  __shared__ __align__(16) u16 As[2][128 * 32];
  __shared__ __align__(16) u16 Bs[2][128 * 32];
  const int tid = threadIdx.x;
  const int w = tid >> 6, lane = tid & 63;
  const int wr = w >> 1, wc = w & 1;
  const int r16 = lane & 15, g = lane >> 4;
  const int nwg = gridDim.x * gridDim.y;
  const int idx = blockIdx.y * gridDim.x + blockIdx.x;
  const int swz = (idx & 7) * (nwg >> 3) + (idx >> 3);
  const int m0 = (swz / gridDim.x) * 128, n0 = (swz % gridDim.x) * 128;
  const int ldrow = lane >> 2;
  const int ldk = (lane & 3) * 8;
  const int NT = K >> 5;

  f32x4 acc[4][4] = {};

  STG_QKV(0, 0);
  asm volatile("s_waitcnt vmcnt(0)" ::: "memory");
  __builtin_amdgcn_s_barrier();

  int cur = 0;
  for (int t = 0; t < NT; ++t) {
    if (t + 1 < NT) STG_QKV(t + 1, cur ^ 1);
    bf16x8 a[4], b[4];
#pragma unroll
    for (int mt = 0; mt < 4; ++mt)
      a[mt] = ldb8(&As[cur][(wr * 64 + mt * 16 + r16) * 32 + g * 8]);
#pragma unroll
    for (int nt = 0; nt < 4; ++nt)
      b[nt] = ldb8(&Bs[cur][(wc * 64 + nt * 16 + r16) * 32 + g * 8]);
#pragma unroll
    for (int mt = 0; mt < 4; ++mt)
#pragma unroll
      for (int nt = 0; nt < 4; ++nt)
        acc[mt][nt] = __builtin_amdgcn_mfma_f32_16x16x32_bf16(
            a[mt], b[nt], acc[mt][nt], 0, 0, 0);
    asm volatile("s_waitcnt vmcnt(0) lgkmcnt(0)" ::: "memory");
    __builtin_amdgcn_s_barrier();
    cur ^= 1;
  }
#pragma unroll
  for (int mt = 0; mt < 4; ++mt)
#pragma unroll
    for (int nt = 0; nt < 4; ++nt)
#pragma unroll
      for (int r = 0; r < 4; ++r) {
        float val = acc[mt][nt][r];
        float other = __shfl_xor(val, 1);  // all lanes participate
        if ((r16 & 1) == 0) {
          float o = val / (1.f + __expf(-val)) * other;  // silu(gate)*up
          int row = m0 + wr * 64 + mt * 16 + g * 4 + r;
          int col = n0 + wc * 64 + nt * 16 + r16;
          Hb[(size_t)row * 2816 + (col >> 1)] = f2bf(o);
        }
      }
}

// ---------------- GEMM 64x64, 2-phase, 512 blocks = 2/CU ------------------
__global__ __launch_bounds__(256) void gemm_bt6464(
    const u16* __restrict__ A, const u16* __restrict__ Bt,
    u16* __restrict__ C, int M, int N, int K) {
  __shared__ __align__(16) u16 As[2][64 * 32];
  __shared__ __align__(16) u16 Bs[2][64 * 32];
  const int tid = threadIdx.x;
  const int w = tid >> 6, lane = tid & 63;
  const int wr = w >> 1, wc = w & 1;
  const int r16 = lane & 15, g = lane >> 4;
  const int nwg = gridDim.x * gridDim.y;
  const int idx = blockIdx.y * gridDim.x + blockIdx.x;
  const int swz = (idx & 7) * (nwg >> 3) + (idx >> 3);  // bijective, nwg%8==0
  const int m0 = (swz / gridDim.x) * 64, n0 = (swz % gridDim.x) * 64;
  const int ldrow = lane >> 2;
  const int ldk = (lane & 3) * 8;
  const int NT = K >> 5;

  f32x4 acc[2][2] = {};

#define STG_6464(tt, b_)                                                  \
  do {                                                                    \
    const int kt_ = (tt) * 32;                                            \
    _Pragma("unroll") for (int i = 0; i < 2; ++i) {                       \
      int chunk = w * 2 + i;                                              \
      if (chunk < 4) {                                                    \
        int row = chunk * 16 + ldrow;                                     \
        gload_lds16(A + (size_t)(m0 + row) * K + kt_ + ldk,               \
                    &As[b_][chunk * 512]);                                \
      } else {                                                            \
        int cb = chunk - 4;                                               \
        int row = cb * 16 + ldrow;                                        \
        gload_lds16(Bt + (size_t)(n0 + row) * K + kt_ + ldk,              \
                    &Bs[b_][cb * 512]);                                   \
      }                                                                   \
    }                                                                     \
  } while (0)

  STG_6464(0, 0);
  asm volatile("s_waitcnt vmcnt(0)" ::: "memory");
  __builtin_amdgcn_s_barrier();

  int cur = 0;
  for (int t = 0; t < NT; ++t) {
    if (t + 1 < NT) STG_6464(t + 1, cur ^ 1);
    bf16x8 a[2], b[2];
#pragma unroll
    for (int mt = 0; mt < 2; ++mt)
      a[mt] = ldb8(&As[cur][(wr * 32 + mt * 16 + r16) * 32 + g * 8]);
#pragma unroll
    for (int nt = 0; nt < 2; ++nt)
      b[nt] = ldb8(&Bs[cur][(wc * 32 + nt * 16 + r16) * 32 + g * 8]);
#pragma unroll
    for (int mt = 0; mt < 2; ++mt)
#pragma unroll
      for (int nt = 0; nt < 2; ++nt)
        acc[mt][nt] = __builtin_amdgcn_mfma_f32_16x16x32_bf16(
            a[mt], b[nt], acc[mt][nt], 0, 0, 0);
    asm volatile("s_waitcnt vmcnt(0) lgkmcnt(0)" ::: "memory");
    __builtin_amdgcn_s_barrier();
    cur ^= 1;
  }
#pragma unroll
  for (int mt = 0; mt < 2; ++mt)
#pragma unroll
    for (int nt = 0; nt < 2; ++nt)
#pragma unroll
      for (int r = 0; r < 4; ++r) {
        int row = m0 + wr * 32 + mt * 16 + g * 4 + r;
        int col = n0 + wc * 32 + nt * 16 + r16;
        C[(size_t)row * N + col] = f2bf(acc[mt][nt][r]);
      }
}

// ---------------- flash attention: R20-exact + wave-uniform skip-rescale --
// Structure = R20 (best: 256 threads, 4 waves, swapped QK^T, batched
// loads). Added: when __all(t8 <= m) the running max didn't grow for ANY
// lane -> alpha == 1 identically -> skip the alpha exp, 4 shfls, and 16
// acc multiplies (exact, no threshold; branch is wave-vote-uniform).
__global__ __launch_bounds__(256, 2) void attn_kernel(
    const u16* __restrict__ qb, const u16* __restrict__ kb,
    const u16* __restrict__ vt, const float* __restrict__ bias,
    u16* __restrict__ attnb) {
  const int bid = blockIdx.x;
  const int swz = (bid & 7) * 64 + (bid >> 3);
  const int h = swz >> 5;
  const int qt = swz & 31;
  const int tid = threadIdx.x;
  const int w = tid >> 6;
  const int lane = tid & 63;
  const int r16 = lane & 15, g = lane >> 4;

  __shared__ __align__(16) u16 P_lds[4][16 * 40];
  __shared__ float acc_s[4][16][64];
  __shared__ float m_s[4][16], l_s[4][16];

  bf16x8 qf0[4], qf1[4];
#pragma unroll
  for (int st = 0; st < 4; ++st) {
    const u16* qrow =
        qb + ((size_t)h * 2048 + qt * 64 + st * 16 + r16) * 64;
    qf0[st] = ldb8(qrow + g * 8);
    qf1[st] = ldb8(qrow + 32 + g * 8);
  }

  f32x4 acc[4][4] = {};
  float m[4], lsum[4];  // per-lane: q = r16
#pragma unroll
  for (int st = 0; st < 4; ++st) { m[st] = -1e30f; lsum[st] = 0.f; }

  const float* bbase = bias + ((size_t)h * 2048 + qt * 64) * 2048;

  const int kv0 = w * 512, kv1 = kv0 + 512;
  for (int kt = kv0; kt < kv1; kt += 32) {
    // batched loads: K, V, and ALL subtiles' bias (one latency exposure)
    bf16x8 ka[2], kc[2];
#pragma unroll
    for (int c = 0; c < 2; ++c) {
      const u16* krow = kb + ((size_t)h * 2048 + kt + c * 16 + r16) * 64;
      ka[c] = ldb8(krow + g * 8);
      kc[c] = ldb8(krow + 32 + g * 8);
    }
    bf16x8 vf[4];
#pragma unroll
    for (int nt = 0; nt < 4; ++nt)
      vf[nt] =
          ldb8(vt + ((size_t)h * 64 + nt * 16 + r16) * 2048 + kt + g * 8);
    float4 bv[4][2];
#pragma unroll
    for (int st = 0; st < 4; ++st) {
      bv[st][0] = *(const float4*)(bbase +
          (size_t)(st * 16 + r16) * 2048 + kt + g * 4);
      bv[st][1] = *(const float4*)(bbase +
          (size_t)(st * 16 + r16) * 2048 + kt + 16 + g * 4);
    }

#pragma unroll
    for (int st = 0; st < 4; ++st) {
      f32x4 sc[2];
#pragma unroll
      for (int c = 0; c < 2; ++c) {
        f32x4 z = {0.f, 0.f, 0.f, 0.f};
        f32x4 t =
            __builtin_amdgcn_mfma_f32_16x16x32_bf16(ka[c], qf0[st], z, 0, 0, 0);
        sc[c] =
            __builtin_amdgcn_mfma_f32_16x16x32_bf16(kc[c], qf1[st], t, 0, 0, 0);
      }
      sc[0][0] += bv[st][0].x; sc[0][1] += bv[st][0].y;
      sc[0][2] += bv[st][0].z; sc[0][3] += bv[st][0].w;
      sc[1][0] += bv[st][1].x; sc[1][1] += bv[st][1].y;
      sc[1][2] += bv[st][1].z; sc[1][3] += bv[st][1].w;

      float t8 = fmaxf(fmaxf(fmaxf(sc[0][0], sc[0][1]), fmaxf(sc[0][2], sc[0][3])),
                       fmaxf(fmaxf(sc[1][0], sc[1][1]), fmaxf(sc[1][2], sc[1][3])));
      t8 = fmaxf(t8, __shfl_xor(t8, 16));
      t8 = fmaxf(t8, __shfl_xor(t8, 32));

      const bool need = __all(t8 <= m[st]) == 0;  // wave-uniform
      float mnew = need ? fmaxf(m[st], t8) : m[st];

      float ps = 0.f;
#pragma unroll
      for (int c = 0; c < 2; ++c)
#pragma unroll
        for (int r = 0; r < 4; ++r) {
          float p = __expf(sc[c][r] - mnew);
          sc[c][r] = p;
          ps += p;
        }

      if (need) {
        float alpha = __expf(m[st] - mnew);
        m[st] = mnew;
        lsum[st] = lsum[st] * alpha + ps;
        float av[4];
#pragma unroll
        for (int r = 0; r < 4; ++r) av[r] = __shfl(alpha, g * 4 + r);
#pragma unroll
        for (int nt = 0; nt < 4; ++nt)
#pragma unroll
          for (int r = 0; r < 4; ++r) acc[st][nt][r] *= av[r];
      } else {
        lsum[st] += ps;  // alpha == 1 exactly
      }

#pragma unroll
      for (int c = 0; c < 2; ++c)
#pragma unroll
        for (int r = 0; r < 4; ++r)
          P_lds[w][r16 * 40 + c * 16 + g * 4 + r] = f2bf(sc[c][r]);
      bf16x8 pf = ldb8(&P_lds[w][r16 * 40 + g * 8]);
#pragma unroll
      for (int nt = 0; nt < 4; ++nt)
        acc[st][nt] = __builtin_amdgcn_mfma_f32_16x16x32_bf16(
            pf, vf[nt], acc[st][nt], 0, 0, 0);
    }
  }

#pragma unroll
  for (int st = 0; st < 4; ++st) {
    __syncthreads();
#pragma unroll
    for (int nt = 0; nt < 4; ++nt)
#pragma unroll
      for (int r = 0; r < 4; ++r)
        acc_s[w][g * 4 + r][nt * 16 + r16] = acc[st][nt][r];
    {
      float t = lsum[st];
      t += __shfl_xor(t, 16);
      t += __shfl_xor(t, 32);
      if (lane < 16) {
        l_s[w][r16] = t;
        m_s[w][r16] = m[st];
      }
    }
    __syncthreads();

    const int row = tid >> 4;
    const int col4 = (tid & 15) * 4;
    float m0v = m_s[0][row], m1v = m_s[1][row], m2v = m_s[2][row],
          m3v = m_s[3][row];
    float mm = fmaxf(fmaxf(m0v, m1v), fmaxf(m2v, m3v));
    float s0 = __expf(m0v - mm), s1 = __expf(m1v - mm);
    float s2 = __expf(m2v - mm), s3 = __expf(m3v - mm);
    float ltot = l_s[0][row] * s0 + l_s[1][row] * s1 + l_s[2][row] * s2 +
                 l_s[3][row] * s3;
    float inv = 1.f / ltot;
    ushort4 ov;
    u16* outp =
        attnb + (size_t)(qt * 64 + st * 16 + row) * 1024 + h * 64 + col4;
#pragma unroll
    for (int j = 0; j < 4; ++j) {
      float v = acc_s[0][row][col4 + j] * s0 + acc_s[1][row][col4 + j] * s1 +
                acc_s[2][row][col4 + j] * s2 + acc_s[3][row][col4 + j] * s3;
      ((u16*)&ov)[j] = f2bf(v * inv);
    }
    *(ushort4*)outp = ov;
  }
}

// ---------------- residual add + RMSNorm ----------------------------------
__global__ __launch_bounds__(256) void addnorm_kernel(
    const float* __restrict__ resid, const u16* __restrict__ delta,
    float* __restrict__ outf, u16* __restrict__ outb) {
  int row = blockIdx.x, tid = threadIdx.x;
  size_t base = (size_t)row * 1024 + tid * 4;
  float4 rv = *(const float4*)(resid + base);
  ushort4 dv = *(const ushort4*)(delta + base);
  float x0 = rv.x + bf2f(dv.x);
  float x1 = rv.y + bf2f(dv.y);
  float x2 = rv.z + bf2f(dv.z);
  float x3 = rv.w + bf2f(dv.w);
  float ss = x0 * x0 + x1 * x1 + x2 * x2 + x3 * x3;
#pragma unroll
  for (int sh = 32; sh >= 1; sh >>= 1) ss += __shfl_xor(ss, sh);
  __shared__ float red[4];
  if ((tid & 63) == 0) red[tid >> 6] = ss;
  __syncthreads();
  float tot = red[0] + red[1] + red[2] + red[3];
  float rstd = rsqrtf(tot * (1.0f / 1024.0f) + 1e-5f);
  float4 ov;
  ov.x = x0 * rstd; ov.y = x1 * rstd; ov.z = x2 * rstd; ov.w = x3 * rstd;
  *(float4*)(outf + base) = ov;
  if (outb) {
    ushort4 ob;
    ob.x = f2bf(ov.x); ob.y = f2bf(ov.y); ob.z = f2bf(ov.z); ob.w = f2bf(ov.w);
    *(ushort4*)(outb + base) = ob;
  }
}

extern "C" void kernel_launch(void* const* d_in, const int* in_sizes, int n_in,
                              void* d_out, int out_size, void* d_ws,
                              size_t ws_size, hipStream_t stream) {
  (void)in_sizes; (void)n_in; (void)out_size; (void)ws_size;
  const float* cosb  = (const float*)d_in[0];
  const float* sinb  = (const float*)d_in[1];
  const float* hidden = (const float*)d_in[2];
  const float* bias  = (const float*)d_in[3];
  const float* w_qkv = (const float*)d_in[4];
  const float* w_o   = (const float*)d_in[5];
  const float* w_gu  = (const float*)d_in[6];
  const float* w_down = (const float*)d_in[7];
  float* out = (float*)d_out;

  char* p = (char*)d_ws;
  auto alloc = [&](size_t bytes) {
    void* r = (void*)p;
    p += (bytes + 255) & ~(size_t)255;
    return r;
  };
  u16* wqkv_t = (u16*)alloc((size_t)3072 * 1024 * 2);
  u16* wo_t   = (u16*)alloc((size_t)1024 * 1024 * 2);
  u16* wgu_t  = (u16*)alloc((size_t)5632 * 1024 * 2);
  u16* wd_t   = (u16*)alloc((size_t)1024 * 2816 * 2);
  u16* xb     = (u16*)alloc((size_t)2048 * 1024 * 2);
  u16* qb     = (u16*)alloc((size_t)16 * 2048 * 64 * 2);
  u16* kb     = (u16*)alloc((size_t)16 * 2048 * 64 * 2);
  u16* vt     = (u16*)alloc((size_t)16 * 2048 * 64 * 2);
  u16* attnb  = (u16*)alloc((size_t)2048 * 1024 * 2);
  u16* ob     = (u16*)alloc((size_t)2048 * 1024 * 2);
  float* x1f  = (float*)alloc((size_t)2048 * 1024 * 4);
  u16* x1b    = (u16*)alloc((size_t)2048 * 1024 * 2);
  u16* hb     = (u16*)alloc((size_t)2048 * 2816 * 2);
  u16* mlpb   = (u16*)alloc((size_t)2048 * 1024 * 2);

  prep_kernel<<<14592, 256, 0, stream>>>(w_qkv, w_o, w_gu, w_down, hidden,
                                         wqkv_t, wo_t, wgu_t, wd_t, xb);

  gemm_qkv_rope<<<dim3(3072 / 128, 2048 / 128), 256, 0, stream>>>(
      xb, wqkv_t, cosb, sinb, qb, kb, vt, 2048, 3072, 1024);
  attn_kernel<<<512, 256, 0, stream>>>(qb, kb, vt, bias, attnb);
  gemm_bt6464<<<dim3(1024 / 64, 2048 / 64), 256, 0, stream>>>(attnb, wo_t, ob, 2048, 1024, 1024);
  addnorm_kernel<<<2048, 256, 0, stream>>>(hidden, ob, x1f, x1b);
  gemm_bt_swiglu<<<dim3(5632 / 128, 2048 / 128), 256, 0, stream>>>(x1b, wgu_t, hb, 2048, 5632, 1024);
  gemm_bt6464<<<dim3(1024 / 64, 2048 / 64), 256, 0, stream>>>(hb, wd_t, mlpb, 2048, 1024, 2816);
  addnorm_kernel<<<2048, 256, 0, stream>>>(x1f, mlpb, out, nullptr);
}